// Round 24
// baseline (62.852 us; speedup 1.0000x reference)
//
#include <hip/hip_runtime.h>

namespace {

constexpr int kB = 256;
constexpr int kS = 512;
constexpr int CHUNK  = 62;                        // useful frames per wave (lane = frame, 2 overlap)
constexpr int NCHUNK = 9;                         // ceil(512/62)
constexpr int NSLOT  = 64;
constexpr int WPB    = 2;                         // waves per WG (r22's best shape)
constexpr int BUFF   = 1536;                      // floats per ring buffer (6144 B)
constexpr int NRING  = 5;                         // ring-5: 30 KB in flight per wave
constexpr int WLDS   = NRING * BUFF;              // 30720 floats? no: 5*1536=7680 floats = 30720 B
// total LDS = 2 * 30720 = 61440 B <= 64 KB static cap

// lambda / count literals -- single-count (each frame term computed ONCE).
constexpr float BSf   = 131072.f;                 // kB*kS
constexpr float K_R1  = 5.0f / (BSf * 3.f);
constexpr float K_R2  = 5.0f / (BSf * 6.f);
constexpr float K_ROT = 1.0f / (BSf * 120.f);
constexpr float K_POS = 2.0f / (BSf * 66.f);
constexpr float K_VEL = 1.0f / (256.f * 511.f * 66.f);
constexpr float K_SMO = 0.5f / (256.f * 510.f * 66.f);
constexpr float K_FLO = 2.0f / (BSf * 2.f);
constexpr float K_CON = 2.0f / (256.f * 511.f * 2.f);
constexpr float K_TIL = 1.0f / (BSf * 3.f);

__device__ __forceinline__ void cont6d(const float a[6], float R[3][3]) {
    float n1 = a[0]*a[0] + a[1]*a[1] + a[2]*a[2];
    float i1 = __frsqrt_rn(fmaxf(n1, 1e-24f));
    float b1x = a[0]*i1, b1y = a[1]*i1, b1z = a[2]*i1;
    float dp  = b1x*a[3] + b1y*a[4] + b1z*a[5];
    float ux = a[3] - b1x*dp, uy = a[4] - b1y*dp, uz = a[5] - b1z*dp;
    float n2 = ux*ux + uy*uy + uz*uz;
    float i2 = __frsqrt_rn(fmaxf(n2, 1e-24f));
    float b2x = ux*i2, b2y = uy*i2, b2z = uz*i2;
    R[0][0] = b1x; R[1][0] = b1y; R[2][0] = b1z;
    R[0][1] = b2x; R[1][1] = b2y; R[2][1] = b2z;
    R[0][2] = b1y*b2z - b1z*b2y;
    R[1][2] = b1z*b2x - b1x*b2z;
    R[2][2] = b1x*b2y - b1y*b2x;
}

// One FK joint, BOTH skeletons in-lane (r19/r20/r22-proven body).
template<bool NEED_R, bool SPINE_J, bool FOOT>
__device__ __forceinline__ void joint_step(
    const float aP[6], const float aT[6], const float* __restrict__ off,
    const float RpP[3][3], const float ppP[3], float RnP[3][3], float pnP[3],
    const float RpT[3][3], const float ppT[3], float RnT[3][3], float pnT[3],
    float wf, float wv, float wa, float& s)
{
    float dsum = 0.f;
    #pragma unroll
    for (int k = 0; k < 6; ++k) { float dd = aP[k] - aT[k]; dsum += dd*dd; }
    s += wf * (K_ROT * dsum);

    const float ox = off[0], oy = off[1], oz = off[2];
    #pragma unroll
    for (int r = 0; r < 3; ++r) {
        pnP[r] = ppP[r] + RpP[r][0]*ox + RpP[r][1]*oy + RpP[r][2]*oz;
        pnT[r] = ppT[r] + RpT[r][0]*ox + RpT[r][1]*oy + RpT[r][2]*oz;
    }

    if constexpr (NEED_R) {
        float RlP[3][3], RlT[3][3];
        cont6d(aP, RlP);
        cont6d(aT, RlT);
        if constexpr (SPINE_J) {
            float t0 = RlP[0][1] - RlT[0][1];
            float t1 = RlP[1][1] - RlT[1][1];
            float t2 = RlP[2][1] - RlT[2][1];
            s += wf * (K_TIL * (t0*t0 + t1*t1 + t2*t2));
        }
        #pragma unroll
        for (int r = 0; r < 3; ++r)
            #pragma unroll
            for (int c = 0; c < 3; ++c) {
                RnP[r][c] = RpP[r][0]*RlP[0][c] + RpP[r][1]*RlP[1][c] + RpP[r][2]*RlP[2][c];
                RnT[r][c] = RpT[r][0]*RlT[0][c] + RpT[r][1]*RlT[1][c] + RpT[r][2]*RlT[2][c];
            }
    }

    float d[3], d1[3];
    #pragma unroll
    for (int r = 0; r < 3; ++r) d[r] = pnP[r] - pnT[r];
    s += wf * (K_POS * (d[0]*d[0] + d[1]*d[1] + d[2]*d[2]));

    float va = 0.f, sa = 0.f;
    #pragma unroll
    for (int r = 0; r < 3; ++r) {
        d1[r]    = __shfl_down(d[r], 1);
        float d2 = __shfl_down(d[r], 2);
        float dv = d1[r] - d[r];            va += dv*dv;
        float ds = d2 - 2.f*d1[r] + d[r];   sa += ds*ds;
    }
    s += wv * (K_VEL * va);
    s += wa * (K_SMO * sa);

    if constexpr (FOOT) {
        s += wf * (K_FLO * (d[1]*d[1]));
        float gx = __shfl_down(pnT[0], 1) - pnT[0];   // gt foot velocity
        float gy = __shfl_down(pnT[1], 1) - pnT[1];
        float gz = __shfl_down(pnT[2], 1) - pnT[2];
        float pvx = gx + (d1[0] - d[0]);              // pred vel = gt vel + delta-d
        float pvy = gy + (d1[1] - d[1]);
        float pvz = gz + (d1[2] - d[2]);
        float planted = (gx*gx + gy*gy + gz*gz < 2.5e-5f) ? 1.f : 0.f;
        s += wv * (K_CON * (planted * sqrtf(pvx*pvx + pvy*pvy + pvz*pvz)));
    }
}

// Ring-5 depth-5 DMA pipeline (30 KB in flight per wave -- 2.5x r23): tests
// the outstanding-bytes-per-wave lever at max LDS. WPB=2, 61440 B/WG, 1152
// WGs. vmcnt(24) through stage 6 (5 stage-groups always in flight), taper
// 18/12/6/0. Waves independent (no barriers). NO occupancy hints.
__global__ __launch_bounds__(64 * WPB)
void motion_loss_kernel(const float* __restrict__ pred,
                        const float* __restrict__ targ,
                        const float* __restrict__ offs,
                        float* __restrict__ acc)
{
    __shared__ float lds[WPB][WLDS];

    const int tid  = threadIdx.x;
    const int wid  = tid >> 6;
    const int lane = tid & 63;          // lane = frame-in-chunk

    const int cg    = blockIdx.x * WPB + wid;     // 0..2303
    const int b     = cg / NCHUNK;
    const int chunk = cg - b * NCHUNK;
    const int s0    = chunk * CHUNK;
    const int s     = s0 + lane;

    const float wf = (lane < CHUNK && s     < kS) ? 1.f : 0.f;
    const float wv = (lane < CHUNK && s + 1 < kS) ? 1.f : 0.f;
    const float wa = (lane < CHUNK && s + 2 < kS) ? 1.f : 0.f;

    const float* predb = pred + (size_t)b * kS * 132;
    const float* targb = targ + (size_t)b * kS * 132;

    // issue one stage's 6 DMA loads (1 KB each): FB = first float of stage
    auto issue = [&](int FB, float* buf) {
        #pragma unroll
        for (int r = 0; r < 6; ++r) {
            const float* tb = (r < 3) ? predb : targb;
            int uu = (r % 3) * 64 + lane;            // 0..191
            int f  = uu / 3;                          // magic-mul
            int c  = uu - f * 3;
            int sf = s0 + f; sf = (sf < kS) ? sf : (kS - 1);
            const float* src = tb + (size_t)sf * 132 + FB + 4 * c;
            __builtin_amdgcn_global_load_lds(
                (const __attribute__((address_space(1))) void*)src,
                (__attribute__((address_space(3))) void*)(buf + r * 256),
                16, 0, 0);
        }
    };

    float* bf0 = lds[wid];
    float* bf1 = lds[wid] + BUFF;
    float* bf2 = lds[wid] + 2 * BUFF;
    float* bf3 = lds[wid] + 3 * BUFF;
    float* bf4 = lds[wid] + 4 * BUFF;

    #define VW(N) do { asm volatile("s_waitcnt vmcnt(" #N ")" ::: "memory"); \
                       __builtin_amdgcn_sched_barrier(0); } while (0)
    #define LW0   do { asm volatile("s_waitcnt lgkmcnt(0)" ::: "memory"); \
                       __builtin_amdgcn_sched_barrier(0); } while (0)

    auto rd6 = [&](const float* base, int jj, float a[6]) {
        const float2* q = reinterpret_cast<const float2*>(base + jj * 6);
        float2 x = q[0], y = q[1], z = q[2];
        a[0]=x.x; a[1]=x.y; a[2]=y.x; a[3]=y.y; a[4]=z.x; a[5]=z.y;
    };

    // prologue: 5 stages in flight (30 loads, 30 KB)
    issue(0,  bf0);     // S0: j0,j1
    issue(12, bf1);     // S1: j2,j3
    issue(24, bf2);     // S2: j4,j5
    issue(36, bf3);     // S3: j6,j7
    issue(48, bf4);     // S4: j8,j9

    float loss = 0.f;
    float R1P[3][3], R3P[3][3], RAP[3][3], RBP[3][3];
    float R1T[3][3], R3T[3][3], RAT[3][3], RBT[3][3];
    float p1[3], p3P[3], pAP[3], pBP[3], pSP[3];
    float          p3T[3], pAT[3], pBT[3], pST[3];
    auto& p1P = p1; auto& p1T = p1;

    #define RD2(BUF) float aP0[6], aT0[6], aP1[6], aT1[6]; { \
        const float* pb_ = (BUF) + lane * 12; \
        const float* tb_ = (BUF) + 768 + lane * 12; \
        rd6(pb_, 0, aP0); rd6(tb_, 0, aT0); rd6(pb_, 1, aP1); rd6(tb_, 1, aT1); }

    #define JS(AP, AT, J, NR, SP, FT, RP, PP, RN, PN) \
        joint_step<NR, SP, FT>(AP, AT, offs + (J)*3, \
            RP##P, PP##P, RN##P, PN##P, RP##T, PP##T, RN##T, PN##T, \
            wf, wv, wa, loss)

    // ---- S0: joints 0,1 (special) ----
    VW(24);
    {
        RD2(bf0);
        LW0; issue(60, bf0);                          // S5: j10,j11
        { // joint 0: root channels 0..2 (in-lane diff); positions identically 0
            float d0 = aP0[0]-aT0[0], d1 = aP0[1]-aT0[1], d2 = aP0[2]-aT0[2];
            loss += wf * (K_R1 * (d0*d0 + d1*d1 + d2*d2));
        }
        { // joint 1: parent identity; pos = offs[1] for both (shared p1)
            float dsum = 0.f;
            #pragma unroll
            for (int k = 0; k < 6; ++k) { float dd = aP1[k]-aT1[k]; dsum += dd*dd; }
            loss += wf * (K_R2 * dsum);
            cont6d(aP1, R1P);
            cont6d(aT1, R1T);
            p1[0] = offs[3]; p1[1] = offs[4]; p1[2] = offs[5];
        }
    }
    // ---- S1: j2 (spine), j3 (save R3) ----
    VW(24);
    {
        RD2(bf1);
        LW0; issue(72, bf1);                          // S6: j12,j13
        JS(aP0, aT0,  2, true , true , false, R1, p1, RA, pA);
        JS(aP1, aT1,  3, true , false, false, RA, pA, R3, p3);
    }
    // ---- S2: j4, j5(leaf) ----
    VW(24);
    {
        RD2(bf2);
        LW0; issue(84, bf2);                          // S7: j14,j15
        JS(aP0, aT0,  4, true , false, false, R3, p3, RA, pA);
        JS(aP1, aT1,  5, false, false, false, RA, pA, RB, pS);
    }
    // ---- S3: j6, j7 ----
    VW(24);
    {
        RD2(bf3);
        LW0; issue(96, bf3);                          // S8: j16,j17
        JS(aP0, aT0,  6, true , false, false, R3, p3, RA, pA);
        JS(aP1, aT1,  7, true , false, false, RA, pA, RB, pB);
    }
    // ---- S4: j8, j9(leaf) ----
    VW(24);
    {
        RD2(bf4);
        LW0; issue(108, bf4);                         // S9: j18,j19
        JS(aP0, aT0,  8, true , false, false, RB, pB, RA, pA);
        JS(aP1, aT1,  9, false, false, false, RA, pA, RB, pS);
    }
    // ---- S5: j10 (R3 dies), j11 ----
    VW(24);
    {
        RD2(bf0);
        LW0; issue(120, bf0);                         // S10: j20,j21
        JS(aP0, aT0, 10, true , false, false, R3, p3, RB, pB);
        JS(aP1, aT1, 11, true , false, false, RB, pB, RA, pA);
    }
    // ---- S6: j12, j13(leaf) (no more issues) ----
    VW(24);
    {
        RD2(bf1);
        JS(aP0, aT0, 12, true , false, false, RA, pA, RB, pB);
        JS(aP1, aT1, 13, false, false, false, RB, pB, RA, pS);
    }
    // ---- S7: j14, j15 ----
    VW(18);
    {
        RD2(bf2);
        JS(aP0, aT0, 14, true , false, false, R1, p1, RA, pA);
        JS(aP1, aT1, 15, true , false, false, RA, pA, RB, pB);
    }
    // ---- S8: j16, j17 ----
    VW(12);
    {
        RD2(bf3);
        JS(aP0, aT0, 16, true , false, false, RB, pB, RA, pA);
        JS(aP1, aT1, 17, true , false, false, RA, pA, RB, pB);
    }
    // ---- S9: j18(FOOT), j19 (R1 dies) ----
    VW(6);
    {
        RD2(bf4);
        JS(aP0, aT0, 18, false, false, true , RB, pB, RA, pS);
        JS(aP1, aT1, 19, true , false, false, R1, p1, RA, pA);
    }
    // ---- S10: j20, j21(FOOT) ----
    VW(0);
    {
        RD2(bf0);
        JS(aP0, aT0, 20, true , false, false, RA, pA, RB, pB);
        JS(aP1, aT1, 21, false, false, true , RB, pB, RA, pS);
    }
    #undef JS
    #undef RD2
    #undef VW
    #undef LW0

    // wave butterfly reduce; one atomic per wave, spread over 64 slots
    float v = loss;
    #pragma unroll
    for (int o = 32; o > 0; o >>= 1) v += __shfl_xor(v, o);
    if (lane == 0) atomicAdd(&acc[cg & (NSLOT - 1)], v);
}

__global__ void finalize_kernel(const float* __restrict__ acc, float* __restrict__ out) {
    float v = acc[threadIdx.x];
    #pragma unroll
    for (int o = 32; o > 0; o >>= 1) v += __shfl_xor(v, o);
    if (threadIdx.x == 0) out[0] = v;
}

} // namespace

extern "C" void kernel_launch(void* const* d_in, const int* in_sizes, int n_in,
                              void* d_out, int out_size, void* d_ws, size_t ws_size,
                              hipStream_t stream) {
    const float* pred = (const float*)d_in[0];
    const float* targ = (const float*)d_in[1];
    const float* offs = (const float*)d_in[2];
    float* acc = (float*)d_ws;

    hipMemsetAsync(acc, 0, NSLOT * sizeof(float), stream);
    const int nblocks = (kB * NCHUNK) / WPB;   // 1152 WGs x 2 waves
    motion_loss_kernel<<<dim3(nblocks), dim3(64 * WPB), 0, stream>>>(pred, targ, offs, acc);
    finalize_kernel<<<1, 64, 0, stream>>>(acc, (float*)d_out);
}

// Round 25
// 53.949 us; speedup vs baseline: 1.1650x; 1.1650x over previous
//
#include <hip/hip_runtime.h>

namespace {

constexpr int kB = 256;
constexpr int kS = 512;
constexpr int CHUNK  = 62;                        // useful frames per wave (lane = frame, 2 overlap)
constexpr int NCHUNK = 9;                         // ceil(512/62)
constexpr int NSLOT  = 64;
constexpr int WPB    = 2;                         // waves per WG (r22 frame)
constexpr int BUFF   = 1536;                      // floats per ring buffer (6144 B)
constexpr int RINGF  = 2 * BUFF;                  // ring-2: 3072 floats
constexpr int SAVROW = 43;                        // per-lane save row (42 used; 43 stride = conflict-free)
constexpr int WTOT   = RINGF + 64 * SAVROW;       // 5824 floats per wave (23296 B)
// total LDS = 2 * 23296 = 46592 B

// lambda / count literals -- single-count (each frame term computed ONCE).
constexpr float BSf   = 131072.f;                 // kB*kS
constexpr float K_R1  = 5.0f / (BSf * 3.f);
constexpr float K_R2  = 5.0f / (BSf * 6.f);
constexpr float K_ROT = 1.0f / (BSf * 120.f);
constexpr float K_POS = 2.0f / (BSf * 66.f);
constexpr float K_VEL = 1.0f / (256.f * 511.f * 66.f);
constexpr float K_SMO = 0.5f / (256.f * 510.f * 66.f);
constexpr float K_FLO = 2.0f / (BSf * 2.f);
constexpr float K_CON = 2.0f / (256.f * 511.f * 2.f);
constexpr float K_TIL = 1.0f / (BSf * 3.f);

__device__ __forceinline__ void cont6d(const float a[6], float R[3][3]) {
    float n1 = a[0]*a[0] + a[1]*a[1] + a[2]*a[2];
    float i1 = __frsqrt_rn(fmaxf(n1, 1e-24f));
    float b1x = a[0]*i1, b1y = a[1]*i1, b1z = a[2]*i1;
    float dp  = b1x*a[3] + b1y*a[4] + b1z*a[5];
    float ux = a[3] - b1x*dp, uy = a[4] - b1y*dp, uz = a[5] - b1z*dp;
    float n2 = ux*ux + uy*uy + uz*uz;
    float i2 = __frsqrt_rn(fmaxf(n2, 1e-24f));
    float b2x = ux*i2, b2y = uy*i2, b2z = uz*i2;
    R[0][0] = b1x; R[1][0] = b1y; R[2][0] = b1z;
    R[0][1] = b2x; R[1][1] = b2y; R[2][1] = b2z;
    R[0][2] = b1y*b2z - b1z*b2y;
    R[1][2] = b1z*b2x - b1x*b2z;
    R[2][2] = b1x*b2y - b1y*b2x;
}

__device__ __forceinline__ void sv9(float* __restrict__ p, const float R[3][3]) {
    #pragma unroll
    for (int r = 0; r < 3; ++r)
        #pragma unroll
        for (int c = 0; c < 3; ++c) p[r*3+c] = R[r][c];
}
__device__ __forceinline__ void ld9(const float* __restrict__ p, float R[3][3]) {
    #pragma unroll
    for (int r = 0; r < 3; ++r)
        #pragma unroll
        for (int c = 0; c < 3; ++c) R[r][c] = p[r*3+c];
}

// One FK joint, BOTH skeletons in-lane (r19/r20/r22-proven body).
template<bool NEED_R, bool SPINE_J, bool FOOT>
__device__ __forceinline__ void joint_step(
    const float aP[6], const float aT[6], const float* __restrict__ off,
    const float RpP[3][3], const float ppP[3], float RnP[3][3], float pnP[3],
    const float RpT[3][3], const float ppT[3], float RnT[3][3], float pnT[3],
    float wf, float wv, float wa, float& s)
{
    float dsum = 0.f;
    #pragma unroll
    for (int k = 0; k < 6; ++k) { float dd = aP[k] - aT[k]; dsum += dd*dd; }
    s += wf * (K_ROT * dsum);

    const float ox = off[0], oy = off[1], oz = off[2];
    #pragma unroll
    for (int r = 0; r < 3; ++r) {
        pnP[r] = ppP[r] + RpP[r][0]*ox + RpP[r][1]*oy + RpP[r][2]*oz;
        pnT[r] = ppT[r] + RpT[r][0]*ox + RpT[r][1]*oy + RpT[r][2]*oz;
    }

    if constexpr (NEED_R) {
        float RlP[3][3], RlT[3][3];
        cont6d(aP, RlP);
        cont6d(aT, RlT);
        if constexpr (SPINE_J) {
            float t0 = RlP[0][1] - RlT[0][1];
            float t1 = RlP[1][1] - RlT[1][1];
            float t2 = RlP[2][1] - RlT[2][1];
            s += wf * (K_TIL * (t0*t0 + t1*t1 + t2*t2));
        }
        #pragma unroll
        for (int r = 0; r < 3; ++r)
            #pragma unroll
            for (int c = 0; c < 3; ++c) {
                RnP[r][c] = RpP[r][0]*RlP[0][c] + RpP[r][1]*RlP[1][c] + RpP[r][2]*RlP[2][c];
                RnT[r][c] = RpT[r][0]*RlT[0][c] + RpT[r][1]*RlT[1][c] + RpT[r][2]*RlT[2][c];
            }
    }

    float d[3], d1[3];
    #pragma unroll
    for (int r = 0; r < 3; ++r) d[r] = pnP[r] - pnT[r];
    s += wf * (K_POS * (d[0]*d[0] + d[1]*d[1] + d[2]*d[2]));

    float va = 0.f, sa = 0.f;
    #pragma unroll
    for (int r = 0; r < 3; ++r) {
        d1[r]    = __shfl_down(d[r], 1);
        float d2 = __shfl_down(d[r], 2);
        float dv = d1[r] - d[r];            va += dv*dv;
        float ds = d2 - 2.f*d1[r] + d[r];   sa += ds*ds;
    }
    s += wv * (K_VEL * va);
    s += wa * (K_SMO * sa);

    if constexpr (FOOT) {
        s += wf * (K_FLO * (d[1]*d[1]));
        float gx = __shfl_down(pnT[0], 1) - pnT[0];   // gt foot velocity
        float gy = __shfl_down(pnT[1], 1) - pnT[1];
        float gz = __shfl_down(pnT[2], 1) - pnT[2];
        float pvx = gx + (d1[0] - d[0]);              // pred vel = gt vel + delta-d
        float pvy = gy + (d1[1] - d[1]);
        float pvz = gz + (d1[2] - d[2]);
        float planted = (gx*gx + gy*gy + gz*gz < 2.5e-5f) ? 1.f : 0.f;
        s += wv * (K_CON * (planted * sqrtf(pvx*pvx + pvy*pvy + pvz*pvz)));
    }
}

// r22 frame (best: 60.7 us) + FK saves (R1, R3, p3 for both skeletons)
// SPILLED TO LDS save rows: -~40 long-lived VGPRs, reloaded at the 6
// restore sites (DS pipe is idle; ~60 extra DS ops/wave). Tests the
// wave-launch-cost model (rate ~ 6500/VGPR waves/us).
// NO occupancy hints; waves independent (no barriers).
__global__ __launch_bounds__(64 * WPB)
void motion_loss_kernel(const float* __restrict__ pred,
                        const float* __restrict__ targ,
                        const float* __restrict__ offs,
                        float* __restrict__ acc)
{
    __shared__ float lds[WPB][WTOT];

    const int tid  = threadIdx.x;
    const int wid  = tid >> 6;
    const int lane = tid & 63;          // lane = frame-in-chunk

    const int cg    = blockIdx.x * WPB + wid;     // 0..2303
    const int b     = cg / NCHUNK;
    const int chunk = cg - b * NCHUNK;
    const int s0    = chunk * CHUNK;
    const int s     = s0 + lane;

    const float wf = (lane < CHUNK && s     < kS) ? 1.f : 0.f;
    const float wv = (lane < CHUNK && s + 1 < kS) ? 1.f : 0.f;
    const float wa = (lane < CHUNK && s + 2 < kS) ? 1.f : 0.f;

    const float* predb = pred + (size_t)b * kS * 132;
    const float* targb = targ + (size_t)b * kS * 132;

    // issue one stage's 6 DMA loads (1 KB each): FB = first float of stage
    auto issue = [&](int FB, float* buf) {
        #pragma unroll
        for (int r = 0; r < 6; ++r) {
            const float* tb = (r < 3) ? predb : targb;
            int uu = (r % 3) * 64 + lane;            // 0..191
            int f  = uu / 3;                          // magic-mul
            int c  = uu - f * 3;
            int sf = s0 + f; sf = (sf < kS) ? sf : (kS - 1);
            const float* src = tb + (size_t)sf * 132 + FB + 4 * c;
            __builtin_amdgcn_global_load_lds(
                (const __attribute__((address_space(1))) void*)src,
                (__attribute__((address_space(3))) void*)(buf + r * 256),
                16, 0, 0);
        }
    };

    float* buf0 = lds[wid];
    float* buf1 = lds[wid] + BUFF;
    float* srow = lds[wid] + RINGF + lane * SAVROW;   // per-lane save row
    // save-row offsets: R1P@0 R1T@9 R3P@18 R3T@27 p3P@36 p3T@39

    #define VW(N) do { asm volatile("s_waitcnt vmcnt(" #N ")" ::: "memory"); \
                       __builtin_amdgcn_sched_barrier(0); } while (0)
    #define LW0   do { asm volatile("s_waitcnt lgkmcnt(0)" ::: "memory"); \
                       __builtin_amdgcn_sched_barrier(0); } while (0)

    auto rd6 = [&](const float* base, int jj, float a[6]) {
        const float2* q = reinterpret_cast<const float2*>(base + jj * 6);
        float2 x = q[0], y = q[1], z = q[2];
        a[0]=x.x; a[1]=x.y; a[2]=y.x; a[3]=y.y; a[4]=z.x; a[5]=z.y;
    };

    // prologue: 2 stages in flight (12 loads)
    issue(0,  buf0);    // S0: j0,j1
    issue(12, buf1);    // S1: j2,j3

    float loss = 0.f;
    float RAP[3][3], RAT[3][3], RBP[3][3], RBT[3][3], RTP[3][3], RTT[3][3];
    float p1[3], pAP[3], pAT[3], pBP[3], pBT[3], pSP[3], pST[3], pLP[3], pLT[3];
    auto& p1P = p1; auto& p1T = p1;

    #define RD2(BUF) float aP0[6], aT0[6], aP1[6], aT1[6]; { \
        const float* pb_ = (BUF) + lane * 12; \
        const float* tb_ = (BUF) + 768 + lane * 12; \
        rd6(pb_, 0, aP0); rd6(tb_, 0, aT0); rd6(pb_, 1, aP1); rd6(tb_, 1, aT1); }

    #define JS(AP, AT, J, NR, SP, FT, RP, PP, RN, PN) \
        joint_step<NR, SP, FT>(AP, AT, offs + (J)*3, \
            RP##P, PP##P, RN##P, PN##P, RP##T, PP##T, RN##T, PN##T, \
            wf, wv, wa, loss)

    // ---- S0: joints 0,1 (special) ----
    VW(6);
    {
        RD2(buf0);
        LW0; issue(24, buf0);                         // S2: j4,j5
        { // joint 0: root channels 0..2 (in-lane diff); positions identically 0
            float d0 = aP0[0]-aT0[0], d1 = aP0[1]-aT0[1], d2 = aP0[2]-aT0[2];
            loss += wf * (K_R1 * (d0*d0 + d1*d1 + d2*d2));
        }
        { // joint 1: parent identity; pos = offs[1] for both (shared p1);
          // R1 computed into temp, spilled to LDS (reloaded at j2/j14/j19)
            float dsum = 0.f;
            #pragma unroll
            for (int k = 0; k < 6; ++k) { float dd = aP1[k]-aT1[k]; dsum += dd*dd; }
            loss += wf * (K_R2 * dsum);
            cont6d(aP1, RTP);
            cont6d(aT1, RTT);
            sv9(srow + 0, RTP);
            sv9(srow + 9, RTT);
            p1[0] = offs[3]; p1[1] = offs[4]; p1[2] = offs[5];
        }
    }
    // ---- S1: j2 (spine, parent R1<-LDS), j3 (result saved to LDS) ----
    VW(6);
    {
        RD2(buf1);
        LW0; issue(36, buf1);                         // S3: j6,j7
        ld9(srow + 0, RTP); ld9(srow + 9, RTT);
        JS(aP0, aT0,  2, true , true , false, RT, p1, RA, pA);
        JS(aP1, aT1,  3, true , false, false, RA, pA, RB, pB);
        sv9(srow + 18, RBP); sv9(srow + 27, RBT);     // R3 -> LDS
        srow[36]=pBP[0]; srow[37]=pBP[1]; srow[38]=pBP[2];
        srow[39]=pBT[0]; srow[40]=pBT[1]; srow[41]=pBT[2];
    }
    // ---- S2: j4 (parent RB=R3 still live), j5(leaf) ----
    VW(6);
    {
        RD2(buf0);
        LW0; issue(48, buf0);                         // S4: j8,j9
        JS(aP0, aT0,  4, true , false, false, RB, pB, RA, pA);
        JS(aP1, aT1,  5, false, false, false, RA, pA, RT, pS);
    }
    // ---- S3: j6 (parent R3<-LDS), j7 ----
    VW(6);
    {
        RD2(buf1);
        LW0; issue(60, buf1);                         // S5: j10,j11
        ld9(srow + 18, RTP); ld9(srow + 27, RTT);
        pLP[0]=srow[36]; pLP[1]=srow[37]; pLP[2]=srow[38];
        pLT[0]=srow[39]; pLT[1]=srow[40]; pLT[2]=srow[41];
        JS(aP0, aT0,  6, true , false, false, RT, pL, RA, pA);
        JS(aP1, aT1,  7, true , false, false, RA, pA, RB, pB);
    }
    // ---- S4: j8, j9(leaf) ----
    VW(6);
    {
        RD2(buf0);
        LW0; issue(72, buf0);                         // S6: j12,j13
        JS(aP0, aT0,  8, true , false, false, RB, pB, RA, pA);
        JS(aP1, aT1,  9, false, false, false, RA, pA, RT, pS);
    }
    // ---- S5: j10 (parent R3<-LDS), j11 ----
    VW(6);
    {
        RD2(buf1);
        LW0; issue(84, buf1);                         // S7: j14,j15
        ld9(srow + 18, RTP); ld9(srow + 27, RTT);
        pLP[0]=srow[36]; pLP[1]=srow[37]; pLP[2]=srow[38];
        pLT[0]=srow[39]; pLT[1]=srow[40]; pLT[2]=srow[41];
        JS(aP0, aT0, 10, true , false, false, RT, pL, RB, pB);
        JS(aP1, aT1, 11, true , false, false, RB, pB, RA, pA);
    }
    // ---- S6: j12, j13(leaf) ----
    VW(6);
    {
        RD2(buf0);
        LW0; issue(96, buf0);                         // S8: j16,j17
        JS(aP0, aT0, 12, true , false, false, RA, pA, RB, pB);
        JS(aP1, aT1, 13, false, false, false, RB, pB, RT, pS);
    }
    // ---- S7: j14 (parent R1<-LDS, pos p1), j15 ----
    VW(6);
    {
        RD2(buf1);
        LW0; issue(108, buf1);                        // S9: j18,j19
        ld9(srow + 0, RTP); ld9(srow + 9, RTT);
        JS(aP0, aT0, 14, true , false, false, RT, p1, RA, pA);
        JS(aP1, aT1, 15, true , false, false, RA, pA, RB, pB);
    }
    // ---- S8: j16, j17 ----
    VW(6);
    {
        RD2(buf0);
        LW0; issue(120, buf0);                        // S10: j20,j21
        JS(aP0, aT0, 16, true , false, false, RB, pB, RA, pA);
        JS(aP1, aT1, 17, true , false, false, RA, pA, RB, pB);
    }
    // ---- S9: j18(FOOT leaf), j19 (parent R1<-LDS, pos p1) ----
    VW(6);
    {
        RD2(buf1);
        JS(aP0, aT0, 18, false, false, true , RB, pB, RT, pS);
        ld9(srow + 0, RTP); ld9(srow + 9, RTT);
        JS(aP1, aT1, 19, true , false, false, RT, p1, RA, pA);
    }
    // ---- S10: j20, j21(FOOT leaf) ----
    VW(0);
    {
        RD2(buf0);
        JS(aP0, aT0, 20, true , false, false, RA, pA, RB, pB);
        JS(aP1, aT1, 21, false, false, true , RB, pB, RT, pS);
    }
    #undef JS
    #undef RD2
    #undef VW
    #undef LW0

    // wave butterfly reduce; one atomic per wave, spread over 64 slots
    float v = loss;
    #pragma unroll
    for (int o = 32; o > 0; o >>= 1) v += __shfl_xor(v, o);
    if (lane == 0) atomicAdd(&acc[cg & (NSLOT - 1)], v);
}

__global__ void finalize_kernel(const float* __restrict__ acc, float* __restrict__ out) {
    float v = acc[threadIdx.x];
    #pragma unroll
    for (int o = 32; o > 0; o >>= 1) v += __shfl_xor(v, o);
    if (threadIdx.x == 0) out[0] = v;
}

} // namespace

extern "C" void kernel_launch(void* const* d_in, const int* in_sizes, int n_in,
                              void* d_out, int out_size, void* d_ws, size_t ws_size,
                              hipStream_t stream) {
    const float* pred = (const float*)d_in[0];
    const float* targ = (const float*)d_in[1];
    const float* offs = (const float*)d_in[2];
    float* acc = (float*)d_ws;

    hipMemsetAsync(acc, 0, NSLOT * sizeof(float), stream);
    const int nblocks = (kB * NCHUNK) / WPB;   // 1152 WGs x 2 waves
    motion_loss_kernel<<<dim3(nblocks), dim3(64 * WPB), 0, stream>>>(pred, targ, offs, acc);
    finalize_kernel<<<1, 64, 0, stream>>>(acc, (float*)d_out);
}